// Round 2
// baseline (215.866 us; speedup 1.0000x reference)
//
#include <hip/hip_runtime.h>
#include <stdint.h>

#define F 256
#define R 64              // rows per block
#define THREADS 256
#define FPAD 264          // LDS row stride in bf16 (+8 -> +16B: 2-way bank alias, free)

typedef __attribute__((ext_vector_type(8))) short short8;
typedef __attribute__((ext_vector_type(4))) float floatx4;

__device__ __forceinline__ uint32_t rotl32(uint32_t x, int d) {
  return (x << d) | (x >> (32 - d));
}

// JAX threefry2x32: 20 rounds, key injections every 4 rounds.
__device__ __forceinline__ void tf2x32(uint32_t k0, uint32_t k1,
                                       uint32_t x0, uint32_t x1,
                                       uint32_t& o0, uint32_t& o1) {
  const uint32_t k2 = k0 ^ k1 ^ 0x1BD11BDAu;
  x0 += k0; x1 += k1;
#define TF_R4(a,b,c,d)                                    \
  x0 += x1; x1 = rotl32(x1,(a)); x1 ^= x0;                \
  x0 += x1; x1 = rotl32(x1,(b)); x1 ^= x0;                \
  x0 += x1; x1 = rotl32(x1,(c)); x1 ^= x0;                \
  x0 += x1; x1 = rotl32(x1,(d)); x1 ^= x0;
  TF_R4(13,15,26,6)
  x0 += k1; x1 += k2 + 1u;
  TF_R4(17,29,16,24)
  x0 += k2; x1 += k0 + 2u;
  TF_R4(13,15,26,6)
  x0 += k0; x1 += k1 + 3u;
  TF_R4(17,29,16,24)
  x0 += k1; x1 += k2 + 4u;
  TF_R4(13,15,26,6)
  x0 += k2; x1 += k0 + 5u;
#undef TF_R4
  o0 = x0; o1 = x1;
}

// JAX uniform(0,100): mantissa-fill to [1,2), -1, scale, clamp at 0.
__device__ __forceinline__ float bits_to_unif(uint32_t bits) {
  uint32_t u = (bits >> 9) | 0x3F800000u;
  return fmaxf(0.0f, (__uint_as_float(u) - 1.0f) * 100.0f);
}

// fp32 -> bf16 RNE
__device__ __forceinline__ uint16_t f2bf(float f) {
  uint32_t u = __float_as_uint(f);
  u += 0x7FFFu + ((u >> 16) & 1u);
  return (uint16_t)(u >> 16);
}

__global__ __launch_bounds__(THREADS) void FloatEmbedding_kernel(
    const float* __restrict__ x, const float* __restrict__ W,
    const float* __restrict__ bias, float* __restrict__ out) {
  __shared__ uint16_t semb[R][FPAD];   // 33.8 KB emb tile, bf16
  __shared__ uint16_t sW[64][FPAD];    // 33.8 KB W g-chunk, bf16, [g_local][f]
  __shared__ uint32_t skey[R][2];

  const int tid  = threadIdx.x;
  const int lane = tid & 63;
  const int wave = tid >> 6;
  const int qd   = lane >> 4;     // quad within wave
  const int l16  = lane & 15;
  const size_t row0 = (size_t)blockIdx.x * R;

  // Phase 0: fold_in per row. base key=(0,42), count=(0, bitcast(x)).
  if (tid < R) {
    uint32_t s = __float_as_uint(x[row0 + tid]);
    uint32_t o0, o1;
    tf2x32(0u, 42u, 0u, s, o0, o1);
    skey[tid][0] = o0; skey[tid][1] = o1;
  }
  __syncthreads();

  // Phase 1: partitionable random_bits: bits[i] = o0 ^ o1, counts (hi,lo)=(0,i).
  // Iter k handles row k, feature i = tid.
  #pragma unroll 2
  for (int k = 0; k < R; ++k) {
    uint32_t k0 = skey[k][0], k1 = skey[k][1];
    uint32_t o0, o1;
    tf2x32(k0, k1, 0u, (uint32_t)tid, o0, o1);
    semb[k][tid] = f2bf(bits_to_unif(o0 ^ o1));
  }
  __syncthreads();

  // Phase 2: out[r][g] = sum_f emb[r][f] * W[g][f] + b[g], via 16x16x32 bf16 MFMA.
  // Loop over 4 g-chunks of 64; stage W chunk fp32->bf16 in LDS each pass.
  for (int gt = 0; gt < 4; ++gt) {
    const float4* Wg4 = (const float4*)(W + (size_t)gt * 64 * F);
    #pragma unroll
    for (int c = 0; c < 16; ++c) {
      int q  = c * THREADS + tid;   // 4096 float4s = 64 g x 64
      int g  = q >> 6;
      int fq = q & 63;              // lanes consecutive -> coalesced 1KB/wave
      float4 w4 = Wg4[g * 64 + fq];
      ushort4 b4 = make_ushort4(f2bf(w4.x), f2bf(w4.y), f2bf(w4.z), f2bf(w4.w));
      *(ushort4*)&sW[g][fq * 4] = b4;
    }
    __syncthreads();

    // Each wave: 16 rows (wave*16..+15) x 64 g (4 tiles of 16). K = 256 = 8 steps.
    floatx4 acc[4];
    #pragma unroll
    for (int n = 0; n < 4; ++n) acc[n] = (floatx4){0.f, 0.f, 0.f, 0.f};

    const uint16_t* arow = &semb[wave * 16 + l16][qd * 8];  // A[m=l16][k=qd*8+j]
    #pragma unroll
    for (int kt = 0; kt < 8; ++kt) {
      short8 a = *(const short8*)(arow + kt * 32);
      #pragma unroll
      for (int n = 0; n < 4; ++n) {
        // B[k][n=g]: lane needs W[g = n*16+l16][f = kt*32 + qd*8 ..+7]
        short8 b = *(const short8*)(&sW[n * 16 + l16][kt * 32 + qd * 8]);
        acc[n] = __builtin_amdgcn_mfma_f32_16x16x32_bf16(a, b, acc[n], 0, 0, 0);
      }
    }

    // Epilogue: D[row=qd*4+reg][col=l16] (m89-verified C/D layout).
    #pragma unroll
    for (int n = 0; n < 4; ++n) {
      int g = gt * 64 + n * 16 + l16;
      float bg = bias[g];
      #pragma unroll
      for (int reg = 0; reg < 4; ++reg) {
        size_t grow = row0 + (size_t)wave * 16 + qd * 4 + reg;
        out[grow * F + g] = acc[n][reg] + bg;
      }
    }
    __syncthreads();  // protect sW before next chunk restage
  }
}

extern "C" void kernel_launch(void* const* d_in, const int* in_sizes, int n_in,
                              void* d_out, int out_size, void* d_ws, size_t ws_size,
                              hipStream_t stream) {
  const float* x = (const float*)d_in[0];
  const float* W = (const float*)d_in[1];
  const float* b = (const float*)d_in[2];
  float* out = (float*)d_out;
  const int nrows = in_sizes[0];           // 131072
  const int blocks = nrows / R;            // 2048
  hipLaunchKernelGGL(FloatEmbedding_kernel, dim3(blocks), dim3(THREADS), 0, stream,
                     x, W, b, out);
}

// Round 3
// 198.948 us; speedup vs baseline: 1.0850x; 1.0850x over previous
//
#include <hip/hip_runtime.h>
#include <stdint.h>

#define F 256
#define R 64               // rows per block
#define THREADS 256
#define EPAD 264           // semb row stride (bf16): +8 elems = +16B -> 2-way alias (free)
#define GCH 32             // g-rows per staged W chunk
#define NCH (F / GCH)      // 8 chunks
#define SLOTS (GCH * F / 8)  // 1024 16B slots per chunk

typedef __attribute__((ext_vector_type(8))) short short8;
typedef __attribute__((ext_vector_type(4))) float floatx4;

__device__ __forceinline__ uint32_t rotl32(uint32_t x, int d) {
  return (x << d) | (x >> (32 - d));   // -> v_alignbit_b32
}

// JAX threefry2x32: 20 rounds, key injections every 4 rounds.
__device__ __forceinline__ void tf2x32(uint32_t k0, uint32_t k1,
                                       uint32_t x0, uint32_t x1,
                                       uint32_t& o0, uint32_t& o1) {
  const uint32_t k2 = k0 ^ k1 ^ 0x1BD11BDAu;
  x0 += k0; x1 += k1;
#define TF_R4(a,b,c,d)                                    \
  x0 += x1; x1 = rotl32(x1,(a)); x1 ^= x0;                \
  x0 += x1; x1 = rotl32(x1,(b)); x1 ^= x0;                \
  x0 += x1; x1 = rotl32(x1,(c)); x1 ^= x0;                \
  x0 += x1; x1 = rotl32(x1,(d)); x1 ^= x0;
  TF_R4(13,15,26,6)
  x0 += k1; x1 += k2 + 1u;
  TF_R4(17,29,16,24)
  x0 += k2; x1 += k0 + 2u;
  TF_R4(13,15,26,6)
  x0 += k0; x1 += k1 + 3u;
  TF_R4(17,29,16,24)
  x0 += k1; x1 += k2 + 4u;
  TF_R4(13,15,26,6)
  x0 += k2; x1 += k0 + 5u;
#undef TF_R4
  o0 = x0; o1 = x1;
}

// JAX uniform(0,100): mantissa-fill [1,2), -1, *100, clamp at 0.
__device__ __forceinline__ float bits_to_unif(uint32_t bits) {
  uint32_t u = (bits >> 9) | 0x3F800000u;
  return fmaxf(0.0f, (__uint_as_float(u) - 1.0f) * 100.0f);
}

// fp32 -> bf16 RNE
__device__ __forceinline__ uint16_t f2bf(float f) {
  uint32_t u = __float_as_uint(f);
  u += 0x7FFFu + ((u >> 16) & 1u);
  return (uint16_t)(u >> 16);
}

__device__ __forceinline__ void gl_lds16(const void* gptr, void* lptr) {
  __builtin_amdgcn_global_load_lds(
      (const __attribute__((address_space(1))) uint32_t*)gptr,
      (__attribute__((address_space(3))) uint32_t*)lptr, 16, 0, 0);
}

// One-time: W fp32 -> bf16, pre-swizzled into global_load_lds slot order.
// Slot s (16B = 8 bf16): row = s>>5, stored granule c = s&31 holds source
// granule c ^ (row&7). 8192 slots total.
__global__ __launch_bounds__(256) void femb_conv(const float* __restrict__ W,
                                                 uint16_t* __restrict__ ws) {
  int s = blockIdx.x * 256 + threadIdx.x;
  int row = s >> 5;
  int c = s & 31;
  int src_c = c ^ (row & 7);
  const float4* src = (const float4*)(W + (size_t)row * F + src_c * 8);
  float4 v0 = src[0], v1 = src[1];
  short8 o;
  o[0] = (short)f2bf(v0.x); o[1] = (short)f2bf(v0.y);
  o[2] = (short)f2bf(v0.z); o[3] = (short)f2bf(v0.w);
  o[4] = (short)f2bf(v1.x); o[5] = (short)f2bf(v1.y);
  o[6] = (short)f2bf(v1.z); o[7] = (short)f2bf(v1.w);
  *(short8*)(ws + (size_t)s * 8) = o;
}

__global__ __launch_bounds__(THREADS, 3) void femb_main(
    const float* __restrict__ x, const uint16_t* __restrict__ Wbf,
    const float* __restrict__ bias, float* __restrict__ out) {
  __shared__ uint16_t semb[R][EPAD];      // 33792 B
  __shared__ uint16_t sW[GCH * F];        // 16384 B, swizzled lane-linear
  __shared__ uint32_t skey[R][2];         // 512 B   (total ~50.7 KB -> 3 blk/CU)

  const int tid  = threadIdx.x;
  const int lane = tid & 63;
  const int wave = tid >> 6;
  const int qd   = lane >> 4;
  const int l16  = lane & 15;
  const size_t row0 = (size_t)blockIdx.x * R;

  // Phase 0: fold_in per row. base key=(0,42), count=(0, bitcast(x)).
  if (tid < R) {
    uint32_t s = __float_as_uint(x[row0 + tid]);
    uint32_t o0, o1;
    tf2x32(0u, 42u, 0u, s, o0, o1);
    skey[tid][0] = o0; skey[tid][1] = o1;
  }
  __syncthreads();

  // Phase 1: partitionable random_bits: bits[i] = o0^o1, counts (0, i).
  // unroll 4 -> 4 independent threefry chains in flight (ILP for the VALU).
  #pragma unroll 4
  for (int k = 0; k < R; ++k) {
    uint32_t o0, o1;
    tf2x32(skey[k][0], skey[k][1], 0u, (uint32_t)tid, o0, o1);
    semb[k][tid] = f2bf(bits_to_unif(o0 ^ o1));
  }
  __syncthreads();

  // Hoist A fragments once: A[m=l16][k=qd*8+j], 8 k-steps.
  const uint16_t* arow = &semb[wave * 16 + l16][qd * 8];
  short8 afrag[8];
  #pragma unroll
  for (int kt = 0; kt < 8; ++kt) afrag[kt] = *(const short8*)(arow + kt * 32);

  // Phase 2: 8 chunks of 32 g-rows; stage pre-swizzled bf16 W via global_load_lds.
  for (int gt = 0; gt < NCH; ++gt) {
    const uint16_t* src = Wbf + (size_t)gt * SLOTS * 8;
    #pragma unroll
    for (int it = 0; it < SLOTS / THREADS; ++it) {       // 4 calls/wave
      int sbase = it * THREADS + wave * 64;              // wave-uniform
      gl_lds16(src + (size_t)(sbase + lane) * 8, &sW[(size_t)sbase * 8]);
    }
    __syncthreads();

    floatx4 acc[2];
    acc[0] = (floatx4){0.f, 0.f, 0.f, 0.f};
    acc[1] = (floatx4){0.f, 0.f, 0.f, 0.f};
    #pragma unroll
    for (int kt = 0; kt < 8; ++kt) {
      #pragma unroll
      for (int n = 0; n < 2; ++n) {
        int g = n * 16 + l16;
        int slot = g * 32 + ((kt * 4 + qd) ^ (g & 7));   // un-swizzle
        short8 b = *(const short8*)&sW[(size_t)slot * 8];
        acc[n] = __builtin_amdgcn_mfma_f32_16x16x32_bf16(afrag[kt], b, acc[n], 0, 0, 0);
      }
    }

    // Epilogue: D[row=qd*4+reg][col=l16] (m89-verified layout).
    #pragma unroll
    for (int n = 0; n < 2; ++n) {
      int gg = gt * GCH + n * 16 + l16;
      float bg = bias[gg];
      #pragma unroll
      for (int reg = 0; reg < 4; ++reg) {
        size_t grow = row0 + (size_t)wave * 16 + qd * 4 + reg;
        out[grow * F + gg] = acc[n][reg] + bg;
      }
    }
    __syncthreads();   // all reads of sW done before next chunk's DMA writes
  }
}

extern "C" void kernel_launch(void* const* d_in, const int* in_sizes, int n_in,
                              void* d_out, int out_size, void* d_ws, size_t ws_size,
                              hipStream_t stream) {
  const float* x = (const float*)d_in[0];
  const float* W = (const float*)d_in[1];
  const float* b = (const float*)d_in[2];
  float* out = (float*)d_out;
  uint16_t* wsbf = (uint16_t*)d_ws;          // 128 KB of ws_size
  const int nrows = in_sizes[0];             // 131072
  const int blocks = nrows / R;              // 2048

  hipLaunchKernelGGL(femb_conv, dim3((F * F / 8) / 256), dim3(256), 0, stream, W, wsbf);
  hipLaunchKernelGGL(femb_main, dim3(blocks), dim3(THREADS), 0, stream,
                     x, wsbf, b, out);
}

// Round 5
// 195.116 us; speedup vs baseline: 1.1063x; 1.0196x over previous
//
#include <hip/hip_runtime.h>
#include <stdint.h>

#define F 256
#define R 64                    // rows per block
#define THREADS 256
#define GCH 32                  // g-rows per staged W chunk
#define NCH (F / GCH)           // 8 chunks
#define CH_SLOTS (GCH * F / 8)  // 1024 16B slots per chunk

typedef __attribute__((ext_vector_type(8))) short short8;
typedef __attribute__((ext_vector_type(4))) float floatx4;

__device__ __forceinline__ uint32_t rotl32(uint32_t x, int d) {
  return (x << d) | (x >> (32 - d));   // v_alignbit_b32
}

// JAX threefry2x32: 20 rounds, key injections every 4 rounds.
__device__ __forceinline__ void tf2x32(uint32_t k0, uint32_t k1,
                                       uint32_t x0, uint32_t x1,
                                       uint32_t& o0, uint32_t& o1) {
  const uint32_t k2 = k0 ^ k1 ^ 0x1BD11BDAu;
  x0 += k0; x1 += k1;
#define TF_R4(a,b,c,d)                                    \
  x0 += x1; x1 = rotl32(x1,(a)); x1 ^= x0;                \
  x0 += x1; x1 = rotl32(x1,(b)); x1 ^= x0;                \
  x0 += x1; x1 = rotl32(x1,(c)); x1 ^= x0;                \
  x0 += x1; x1 = rotl32(x1,(d)); x1 ^= x0;
  TF_R4(13,15,26,6)
  x0 += k1; x1 += k2 + 1u;
  TF_R4(17,29,16,24)
  x0 += k2; x1 += k0 + 2u;
  TF_R4(13,15,26,6)
  x0 += k0; x1 += k1 + 3u;
  TF_R4(17,29,16,24)
  x0 += k1; x1 += k2 + 4u;
  TF_R4(13,15,26,6)
  x0 += k2; x1 += k0 + 5u;
#undef TF_R4
  o0 = x0; o1 = x1;
}

// fp32 -> bf16 RNE
__device__ __forceinline__ uint32_t f2bf(float f) {
  uint32_t u = __float_as_uint(f);
  u += 0x7FFFu + ((u >> 16) & 1u);
  return u >> 16;
}

// partitionable threefry feature -> bf16(uniform[0,100)).
// bits * (100 * 2^-32); matches ((bits>>9)|1.0f)-1)*100 within 1.2e-5.
// NOTE: 2.3283064365386963e-8 IS 100*2^-32 — do not multiply by 100 again
// (R4 bug: did exactly that -> emb in [0,10000) -> absmax 23570).
__device__ __forceinline__ uint32_t feat_bf16(uint32_t k0, uint32_t k1, uint32_t i) {
  uint32_t o0, o1;
  tf2x32(k0, k1, 0u, i, o0, o1);
  return f2bf((float)(o0 ^ o1) * 2.3283064365386963e-8f);
}

__device__ __forceinline__ void gl_lds16(const void* gptr, void* lptr) {
  __builtin_amdgcn_global_load_lds(
      (const __attribute__((address_space(1))) uint32_t*)gptr,
      (__attribute__((address_space(3))) uint32_t*)lptr, 16, 0, 0);
}

// One-time: W fp32 -> bf16 TRANSPOSED into DMA slot order.
// Slot s: chunk gt=s>>10, c=(s>>5)&31 (k-granule), g=s&31.
// Holds W[gt*32+g][c*8 .. c*8+7] as 8 bf16.
__global__ __launch_bounds__(256) void femb_conv(const float* __restrict__ W,
                                                 uint16_t* __restrict__ ws) {
  int s = blockIdx.x * 256 + threadIdx.x;   // 8192 slots
  int gt = s >> 10;
  int c = (s >> 5) & 31;
  int g = s & 31;
  const float4* src = (const float4*)(W + (size_t)(gt * GCH + g) * F + c * 8);
  float4 v0 = src[0], v1 = src[1];
  short8 o;
  o[0] = (short)f2bf(v0.x); o[1] = (short)f2bf(v0.y);
  o[2] = (short)f2bf(v0.z); o[3] = (short)f2bf(v0.w);
  o[4] = (short)f2bf(v1.x); o[5] = (short)f2bf(v1.y);
  o[6] = (short)f2bf(v1.z); o[7] = (short)f2bf(v1.w);
  *(short8*)(ws + (size_t)s * 8) = o;
}

__global__ __launch_bounds__(THREADS, 4) void femb_main(
    const float* __restrict__ x, const uint16_t* __restrict__ Wbf,
    const float* __restrict__ bias, float* __restrict__ out) {
  __shared__ uint16_t sW[2][GCH * F];   // 2 x 16 KB, DMA slot order

  const int tid  = threadIdx.x;
  const int lane = tid & 63;
  const int wave = tid >> 6;
  const int qd   = lane >> 4;
  const int l16  = lane & 15;
  const size_t row0 = (size_t)blockIdx.x * R;
  const int myrow = (int)row0 + wave * 16 + l16;

  // Load x early so its waitcnt doesn't wait on the DMA queue.
  float xv = x[myrow];

  // Prefetch W chunk 0 into buf 0 (latency hidden behind the RNG burn).
  {
    const uint16_t* src = Wbf;
    #pragma unroll
    for (int it = 0; it < CH_SLOTS / THREADS; ++it) {
      int sbase = it * THREADS + wave * 64;           // wave-uniform base
      gl_lds16(src + (size_t)(sbase + lane) * 8, &sW[0][(size_t)sbase * 8]);
    }
  }

  // fold_in: key = threefry((0,42), (0, bitcast(x))). 4x redundant across qd.
  uint32_t k0, k1;
  tf2x32(0u, 42u, 0u, __float_as_uint(xv), k0, k1);

  // RNG straight into A-fragments: lane (qd,l16) of wave w owns
  // A[m=l16][k=qd*8+j] for row w*16+l16 -> features kt*32+qd*8+j.
  short8 afrag[8];
  #pragma unroll
  for (int kt = 0; kt < 8; ++kt) {
    const uint32_t fb = (uint32_t)(kt * 32 + qd * 8);
    uint32_t w32[4];
    #pragma unroll
    for (int p = 0; p < 4; ++p) {                     // 8 independent chains
      uint32_t lo = feat_bf16(k0, k1, fb + 2 * p);
      uint32_t hi = feat_bf16(k0, k1, fb + 2 * p + 1);
      w32[p] = lo | (hi << 16);
    }
    union { uint32_t w[4]; short8 s; } u;
    u.w[0] = w32[0]; u.w[1] = w32[1]; u.w[2] = w32[2]; u.w[3] = w32[3];
    afrag[kt] = u.s;
  }

  // Chunk loop: MFMA chunk gt from buf gt&1 while DMA'ing gt+1 into the other.
  for (int gt = 0; gt < NCH; ++gt) {
    __syncthreads();   // chunk gt DMA drained (vmcnt0) + prev buf reads done
    if (gt + 1 < NCH) {
      const uint16_t* src = Wbf + (size_t)(gt + 1) * CH_SLOTS * 8;
      #pragma unroll
      for (int it = 0; it < CH_SLOTS / THREADS; ++it) {
        int sbase = it * THREADS + wave * 64;
        gl_lds16(src + (size_t)(sbase + lane) * 8,
                 &sW[(gt + 1) & 1][(size_t)sbase * 8]);
      }
    }

    const uint16_t* buf = sW[gt & 1];
    floatx4 acc[2];
    acc[0] = (floatx4){0.f, 0.f, 0.f, 0.f};
    acc[1] = (floatx4){0.f, 0.f, 0.f, 0.f};
    #pragma unroll
    for (int kt = 0; kt < 8; ++kt) {
      int c = kt * 4 + qd;
      #pragma unroll
      for (int n = 0; n < 2; ++n) {
        // slot = c*32 + n*16 + l16: 16 consecutive b128 per 16-lane group.
        short8 b = *(const short8*)&buf[(size_t)(c * 32 + n * 16 + l16) * 8];
        acc[n] = __builtin_amdgcn_mfma_f32_16x16x32_bf16(afrag[kt], b, acc[n], 0, 0, 0);
      }
    }

    // Epilogue: D[row=qd*4+reg][col=l16] (m89-verified layout).
    #pragma unroll
    for (int n = 0; n < 2; ++n) {
      int g = gt * GCH + n * 16 + l16;
      float bg = bias[g];
      #pragma unroll
      for (int reg = 0; reg < 4; ++reg) {
        size_t grow = row0 + (size_t)wave * 16 + qd * 4 + reg;
        out[grow * F + g] = acc[n][reg] + bg;
      }
    }
  }
}

extern "C" void kernel_launch(void* const* d_in, const int* in_sizes, int n_in,
                              void* d_out, int out_size, void* d_ws, size_t ws_size,
                              hipStream_t stream) {
  const float* x = (const float*)d_in[0];
  const float* W = (const float*)d_in[1];
  const float* b = (const float*)d_in[2];
  float* out = (float*)d_out;
  uint16_t* wsbf = (uint16_t*)d_ws;          // 128 KB of ws_size
  const int nrows = in_sizes[0];             // 131072
  const int blocks = nrows / R;              // 2048

  hipLaunchKernelGGL(femb_conv, dim3((F * F / 8) / 256), dim3(256), 0, stream, W, wsbf);
  hipLaunchKernelGGL(femb_main, dim3(blocks), dim3(THREADS), 0, stream,
                     x, wsbf, b, out);
}